// Round 7
// baseline (390.211 us; speedup 1.0000x reference)
//
#include <hip/hip_runtime.h>
#include <hip/hip_bf16.h>
#include <cstdint>
#include <cstddef>

#define B_DIM 64
#define K_DIM 2048
#define D_DIM 32400
#define KTILE 128
#define KS    128   // p1 d-step (512B per row per visit)

typedef __bf16 bf16x8 __attribute__((ext_vector_type(8)));
typedef float f32x4 __attribute__((ext_vector_type(4)));

union U128 { uint4 u; bf16x8 b; };

__device__ inline bf16x8 asbf(uint4 u) { U128 x; x.u = u; return x.b; }

__device__ inline uint4 neg4(uint4 u) {
    u.x ^= 0x80008000u; u.y ^= 0x80008000u; u.z ^= 0x80008000u; u.w ^= 0x80008000u;
    return u;
}

__device__ inline f32x4 mfma16(bf16x8 a, bf16x8 b, f32x4 c) {
    return __builtin_amdgcn_mfma_f32_16x16x32_bf16(a, b, c, 0, 0, 0);
}

// guarded float4 load: element index d within row pointer p, limit dlim
__device__ inline f32x4 ld4g(const float* __restrict__ p, int d, int dlim) {
    f32x4 r;
    if (d + 4 <= dlim) {
        float4 v = *reinterpret_cast<const float4*>(p + d);
        r[0] = v.x; r[1] = v.y; r[2] = v.z; r[3] = v.w;
    } else {
        #pragma unroll
        for (int j = 0; j < 4; ++j) r[j] = (d + j < dlim) ? p[d + j] : 0.0f;
    }
    return r;
}

// guarded 8x bf16 (16B) load
__device__ inline uint4 ld8bf(const __bf16* __restrict__ p, int d, int dlim) {
    if (d + 8 <= dlim) return *reinterpret_cast<const uint4*>(p + d);
    union { uint4 u; __bf16 h[8]; } x;
    #pragma unroll
    for (int j = 0; j < 8; ++j) x.h[j] = (d + j < dlim) ? p[d + j] : (__bf16)0.0f;
    return x.u;
}

// pack two floats -> dword of 2 bf16 (lo = a, hi = b)
__device__ inline uint32_t pk(float a, float b) {
    union { __bf16 h[2]; uint32_t u; } x;
    x.h[0] = (__bf16)a; x.h[1] = (__bf16)b;
    return x.u;
}

// ---------------------------------------------------------------------------
// Phase 0: X f32 -> bf16
// ---------------------------------------------------------------------------
__global__ __launch_bounds__(256) void xbf_kernel(
    const float* __restrict__ Xre, const float* __restrict__ Xim,
    __bf16* __restrict__ XreB, __bf16* __restrict__ XimB)
{
    const int i = (blockIdx.x * 256 + threadIdx.x) * 4;
    if (i < B_DIM * D_DIM) {
        float4 a = *reinterpret_cast<const float4*>(Xre + i);
        float4 b = *reinterpret_cast<const float4*>(Xim + i);
        *(uint2*)(XreB + i) = make_uint2(pk(a.x, a.y), pk(a.z, a.w));
        *(uint2*)(XimB + i) = make_uint2(pk(b.x, b.y), pk(b.z, b.w));
    }
}

// ---------------------------------------------------------------------------
// Phase 1 v2: coeffs[b,k] = (sum_d X[b,d]*conj(bases[k,d])) * w[k], split-D.
// KS=128: bases rows visited in 512B-contiguous chunks; staging = 32 lanes x
// float4 = 512B per instruction. Bases-only LDS [2][128][128] bf16 = 64 KB,
// XOR-swizzled (byte ^= (row&7)<<4) -> uniform bank load on b128 fragment
// reads. X (bf16, L2/L3-hot 8.3MB) is read as A-fragments directly from
// global per MFMA step. Grid x=ktg (xcd=ktg%8).
// ---------------------------------------------------------------------------
template <bool XBF>
__global__ __launch_bounds__(256, 2) void p1_coeffs(
    const float* __restrict__ XreF, const float* __restrict__ XimF,
    const __bf16* __restrict__ XreB, const __bf16* __restrict__ XimB,
    const float* __restrict__ Bre, const float* __restrict__ Bim,
    const float* __restrict__ Wre, const float* __restrict__ Wim,
    float* __restrict__ Cre, float* __restrict__ Cim)
{
    __shared__ __align__(16) __bf16 sB[2][KTILE][KS];  // 64 KB, swizzled

    const int ktg = blockIdx.x;       // 16 k-groups of 128  (xcd = ktg%8)
    const int dc  = blockIdx.y;       // 32 d-chunks of 1024
    const int tid  = threadIdx.x;
    const int lane = tid & 63;
    const int w    = tid >> 6;
    const int r    = lane & 15;
    const int g    = lane >> 4;

    const int kbase  = ktg * KTILE;
    const int dstart = dc * 1024;
    const int dend   = min(dstart + 1024, D_DIM);
    const int nsteps = (dend - dstart + KS - 1) / KS;

    // staging map: 32-lane groups, 512B contiguous per row per instruction
    const int srow = tid >> 5;          // 0..7 (+8 per j)
    const int sdx  = (tid & 31) * 4;    // f32-elem offset 0..124

    uint2 stb[32];  // 16 rows re + 16 rows im, 4 bf16 each

    auto LOADS = [&](int s) {
        const int dg = dstart + s * KS + sdx;
        #pragma unroll
        for (int j = 0; j < 16; ++j) {
            const int row = j * 8 + srow;
            f32x4 a = ld4g(Bre + (size_t)(kbase + row) * D_DIM, dg, dend);
            f32x4 b = ld4g(Bim + (size_t)(kbase + row) * D_DIM, dg, dend);
            stb[j]      = make_uint2(pk(a[0], a[1]), pk(a[2], a[3]));
            stb[16 + j] = make_uint2(pk(b[0], b[1]), pk(b[2], b[3]));
        }
    };

    // swizzled byte offset within one matrix plane
    auto lds_off = [&](int row, int delem) -> uint32_t {
        return ((uint32_t)(row * (KS * 2) + delem * 2)) ^ (uint32_t)((row & 7) << 4);
    };

    auto WRITE = [&]() {
        char* b0 = (char*)&sB[0][0][0];
        char* b1 = (char*)&sB[1][0][0];
        #pragma unroll
        for (int j = 0; j < 16; ++j) {
            const int row = j * 8 + srow;
            const uint32_t off = lds_off(row, sdx);
            *(uint2*)(b0 + off) = stb[j];
            *(uint2*)(b1 + off) = stb[16 + j];
        }
    };

    const int m0  = (w & 1) * 32;     // local b quadrant (32 rows)
    const int nl0 = (w >> 1) * 64;    // local k span (64 cols)

    f32x4 accRe[2][4] = {};
    f32x4 accIm[2][4] = {};

    auto COMPUTE = [&](int s) {
        const char* b0 = (const char*)&sB[0][0][0];
        const char* b1 = (const char*)&sB[1][0][0];
        #pragma unroll
        for (int kk = 0; kk < 4; ++kk) {
            const int del = kk * 32 + g * 8;
            const int dg  = dstart + s * KS + del;
            uint4 xre[2], xim[2], bre[4], bim[4];
            #pragma unroll
            for (int ms = 0; ms < 2; ++ms) {
                const size_t xo = (size_t)(m0 + ms * 16 + r) * D_DIM;
                if (XBF) {
                    xre[ms] = ld8bf(XreB + xo, dg, dend);
                    xim[ms] = ld8bf(XimB + xo, dg, dend);
                } else {
                    f32x4 a0 = ld4g(XreF + xo, dg, dend), a1 = ld4g(XreF + xo, dg + 4, dend);
                    f32x4 c0 = ld4g(XimF + xo, dg, dend), c1 = ld4g(XimF + xo, dg + 4, dend);
                    xre[ms] = make_uint4(pk(a0[0], a0[1]), pk(a0[2], a0[3]), pk(a1[0], a1[1]), pk(a1[2], a1[3]));
                    xim[ms] = make_uint4(pk(c0[0], c0[1]), pk(c0[2], c0[3]), pk(c1[0], c1[1]), pk(c1[2], c1[3]));
                }
            }
            #pragma unroll
            for (int ns = 0; ns < 4; ++ns) {
                const uint32_t off = lds_off(nl0 + ns * 16 + r, del);
                bre[ns] = *(const uint4*)(b0 + off);
                bim[ns] = *(const uint4*)(b1 + off);
            }
            #pragma unroll
            for (int ms = 0; ms < 2; ++ms)
            #pragma unroll
            for (int ns = 0; ns < 4; ++ns) {
                // C_re += Xre*Bre + Xim*Bim ; C_im += Xim*Bre - Xre*Bim
                accRe[ms][ns] = mfma16(asbf(xre[ms]), asbf(bre[ns]), accRe[ms][ns]);
                accRe[ms][ns] = mfma16(asbf(xim[ms]), asbf(bim[ns]), accRe[ms][ns]);
                accIm[ms][ns] = mfma16(asbf(xim[ms]), asbf(bre[ns]), accIm[ms][ns]);
                accIm[ms][ns] = mfma16(asbf(neg4(xre[ms])), asbf(bim[ns]), accIm[ms][ns]);
            }
        }
    };

    LOADS(0); WRITE(); __syncthreads();
    for (int s = 0; s < nsteps; ++s) {
        if (s + 1 < nsteps) LOADS(s + 1);
        COMPUTE(s);
        if (s + 1 < nsteps) {
            __syncthreads();   // all fragment reads of the buffer done
            WRITE();           // overwrite with s+1 tile
            __syncthreads();   // writes visible
        }
    }

    // epilogue: scale by w[k], atomic accumulate (C/D: col=lane&15, row=g*4+i)
    #pragma unroll
    for (int ms = 0; ms < 2; ++ms)
    #pragma unroll
    for (int ns = 0; ns < 4; ++ns) {
        const int kb = kbase + nl0 + ns * 16 + r;
        const float wre = Wre[kb], wim = Wim[kb];
        #pragma unroll
        for (int i = 0; i < 4; ++i) {
            const int b = m0 + ms * 16 + g * 4 + i;
            const float cre = accRe[ms][ns][i];
            const float cim = accIm[ms][ns][i];
            atomicAdd(&Cre[b * K_DIM + kb], cre * wre - cim * wim);
            atomicAdd(&Cim[b * K_DIM + kb], cre * wim + cim * wre);
        }
    }
}

// ---------------------------------------------------------------------------
// Phase 1.5: coeffs f32 -> bf16
// ---------------------------------------------------------------------------
__global__ __launch_bounds__(256) void cbf_kernel(
    const float* __restrict__ Cre, const float* __restrict__ Cim,
    __bf16* __restrict__ CreBf, __bf16* __restrict__ CimBf)
{
    const int i = blockIdx.x * 256 + threadIdx.x;
    if (i < B_DIM * K_DIM) {
        CreBf[i] = (__bf16)Cre[i];
        CimBf[i] = (__bf16)Cim[i];
    }
}

// ---------------------------------------------------------------------------
// Phase 2: out[b,d] += sum_{k in half} coeffs[b,k] * bases[k,d]
// K split in 2 halves (grid.y); f32 atomicAdd into pre-zeroed out.
// bases tile [64 k][64 d] staged TRANSPOSED into LDS [d][k] (bf16).
// ---------------------------------------------------------------------------
#define P2_STRIDE 72  // 64 k + 8 pad (144B rows, 16B aligned)

template <bool WIM>
__global__ __launch_bounds__(256) void p2_project(
    const float* __restrict__ Bre, const float* __restrict__ Bim,
    const __bf16* __restrict__ CreBf, const __bf16* __restrict__ CimBf,
    float* __restrict__ out)
{
    __shared__ __align__(16) __bf16 sT[2][2][64][P2_STRIDE];  // [buf][mat][d][k]

    const int dt = blockIdx.x;
    const int kh = blockIdx.y;        // k half: 0 -> [0,1024), 1 -> [1024,2048)
    const int d0 = dt * 64;
    const int khbase = kh * (K_DIM / 2);
    const int tid  = threadIdx.x;
    const int lane = tid & 63;
    const int w    = tid >> 6;
    const int r    = lane & 15;
    const int g    = lane >> 4;

    // staging map: thread t handles k-rows 4*(t>>4)..+3 at d = (t&15)*4
    const int kq = tid >> 4;          // 0..15
    const int ds = (tid & 15) * 4;    // 0..60

    f32x4 st[8];  // 4 k-rows x {re, im}

    auto LOADS = [&](int t) {
        const int k0 = khbase + t * 64;
        #pragma unroll
        for (int j = 0; j < 4; ++j) {
            const size_t ro = (size_t)(k0 + kq * 4 + j) * D_DIM;
            st[j]     = ld4g(Bre + ro, d0 + ds, D_DIM);
            st[4 + j] = ld4g(Bim + ro, d0 + ds, D_DIM);
        }
    };

    auto WRITE = [&](int buf) {
        #pragma unroll
        for (int i = 0; i < 4; ++i) {
            *(uint2*)&sT[buf][0][ds + i][kq * 4] =
                make_uint2(pk(st[0][i], st[1][i]), pk(st[2][i], st[3][i]));
            *(uint2*)&sT[buf][1][ds + i][kq * 4] =
                make_uint2(pk(st[4][i], st[5][i]), pk(st[6][i], st[7][i]));
        }
    };

    const int m0  = (w & 1) * 32;     // b quadrant
    const int nl0 = (w >> 1) * 32;    // local d quadrant

    f32x4 accRe[2][2] = {};
    f32x4 accIm[2][2] = {};

    auto COMPUTE = [&](int t, int buf) {
        const int k0 = khbase + t * 64;
        uint4 aRe[2][2], aIm[2][2];
        #pragma unroll
        for (int ms = 0; ms < 2; ++ms) {
            const size_t rowo = (size_t)(m0 + ms * 16 + r) * K_DIM;
            #pragma unroll
            for (int kk = 0; kk < 2; ++kk) {
                aRe[ms][kk] = *(const uint4*)&CreBf[rowo + k0 + kk * 32 + g * 8];
                aIm[ms][kk] = *(const uint4*)&CimBf[rowo + k0 + kk * 32 + g * 8];
            }
        }
        #pragma unroll
        for (int kk = 0; kk < 2; ++kk) {
            uint4 bre[2], bim[2];
            #pragma unroll
            for (int ns = 0; ns < 2; ++ns) {
                bre[ns] = *(const uint4*)&sT[buf][0][nl0 + ns * 16 + r][kk * 32 + g * 8];
                bim[ns] = *(const uint4*)&sT[buf][1][nl0 + ns * 16 + r][kk * 32 + g * 8];
            }
            #pragma unroll
            for (int ms = 0; ms < 2; ++ms)
            #pragma unroll
            for (int ns = 0; ns < 2; ++ns) {
                // out_re += cre*Bre - cim*Bim ; out_im += cre*Bim + cim*Bre
                accRe[ms][ns] = mfma16(asbf(aRe[ms][kk]), asbf(bre[ns]), accRe[ms][ns]);
                accRe[ms][ns] = mfma16(asbf(neg4(aIm[ms][kk])), asbf(bim[ns]), accRe[ms][ns]);
                if (WIM) {
                    accIm[ms][ns] = mfma16(asbf(aRe[ms][kk]), asbf(bim[ns]), accIm[ms][ns]);
                    accIm[ms][ns] = mfma16(asbf(aIm[ms][kk]), asbf(bre[ns]), accIm[ms][ns]);
                }
            }
        }
    };

    const int NT = (K_DIM / 2) / 64;  // 16
    LOADS(0); WRITE(0); __syncthreads();
    for (int t = 0; t < NT; ++t) {
        if (t + 1 < NT) LOADS(t + 1);
        COMPUTE(t, t & 1);
        if (t + 1 < NT) WRITE((t + 1) & 1);
        __syncthreads();
    }

    #pragma unroll
    for (int ms = 0; ms < 2; ++ms)
    #pragma unroll
    for (int ns = 0; ns < 2; ++ns) {
        const int d = d0 + nl0 + ns * 16 + r;
        if (d < D_DIM) {
            #pragma unroll
            for (int i = 0; i < 4; ++i) {
                const int b = m0 + ms * 16 + g * 4 + i;
                if (!WIM) {
                    atomicAdd(&out[(size_t)b * D_DIM + d], accRe[ms][ns][i]);
                } else {
                    atomicAdd(&out[((size_t)b * D_DIM + d) * 2],     accRe[ms][ns][i]);
                    atomicAdd(&out[((size_t)b * D_DIM + d) * 2 + 1], accIm[ms][ns][i]);
                }
            }
        }
    }
}

extern "C" void kernel_launch(void* const* d_in, const int* in_sizes, int n_in,
                              void* d_out, int out_size, void* d_ws, size_t ws_size,
                              hipStream_t stream) {
    const float* Xre = (const float*)d_in[0];
    const float* Xim = (const float*)d_in[1];
    const float* Bre = (const float*)d_in[2];
    const float* Bim = (const float*)d_in[3];
    const float* Wre = (const float*)d_in[4];
    const float* Wim = (const float*)d_in[5];

    float*  Cre   = (float*)d_ws;                          // 512 KB
    float*  Cim   = Cre + B_DIM * K_DIM;                   // 512 KB
    __bf16* CreBf = (__bf16*)(Cim + B_DIM * K_DIM);        // 256 KB
    __bf16* CimBf = CreBf + B_DIM * K_DIM;                 // 256 KB
    __bf16* XreB  = CimBf + B_DIM * K_DIM;                 // 4.15 MB
    __bf16* XimB  = XreB + (size_t)B_DIM * D_DIM;          // 4.15 MB

    const size_t need = (size_t)2 * B_DIM * K_DIM * sizeof(float)
                      + (size_t)2 * B_DIM * K_DIM * sizeof(__bf16)
                      + (size_t)2 * B_DIM * D_DIM * sizeof(__bf16);
    const bool xbf = ws_size >= need;

    (void)hipMemsetAsync(d_ws, 0, (size_t)2 * B_DIM * K_DIM * sizeof(float), stream);
    (void)hipMemsetAsync(d_out, 0, (size_t)out_size * sizeof(float), stream);

    dim3 g1(K_DIM / KTILE, 32);  // x = k-group (drives XCD assignment), y = d-chunk
    if (xbf) {
        xbf_kernel<<<(B_DIM * D_DIM / 4 + 255) / 256, 256, 0, stream>>>(Xre, Xim, XreB, XimB);
        p1_coeffs<true><<<g1, 256, 0, stream>>>(Xre, Xim, XreB, XimB, Bre, Bim, Wre, Wim, Cre, Cim);
    } else {
        p1_coeffs<false><<<g1, 256, 0, stream>>>(Xre, Xim, XreB, XimB, Bre, Bim, Wre, Wim, Cre, Cim);
    }

    cbf_kernel<<<(B_DIM * K_DIM + 255) / 256, 256, 0, stream>>>(Cre, Cim, CreBf, CimBf);

    const int ndt = (D_DIM + 63) / 64;  // 507
    dim3 g2(ndt, 2);
    if (out_size == 2 * B_DIM * D_DIM) {
        p2_project<true><<<g2, 256, 0, stream>>>(Bre, Bim, CreBf, CimBf, (float*)d_out);
    } else {
        p2_project<false><<<g2, 256, 0, stream>>>(Bre, Bim, CreBf, CimBf, (float*)d_out);
    }
}

// Round 8
// 311.936 us; speedup vs baseline: 1.2509x; 1.2509x over previous
//
#include <hip/hip_runtime.h>
#include <hip/hip_bf16.h>
#include <cstdint>
#include <cstddef>

#define B_DIM 64
#define K_DIM 2048
#define D_DIM 32400
#define KTILE 128

typedef __bf16 bf16x8 __attribute__((ext_vector_type(8)));
typedef float f32x4 __attribute__((ext_vector_type(4)));

union U128 { uint4 u; bf16x8 b; };

__device__ inline bf16x8 asbf(uint4 u) { U128 x; x.u = u; return x.b; }

__device__ inline uint4 neg4(uint4 u) {
    u.x ^= 0x80008000u; u.y ^= 0x80008000u; u.z ^= 0x80008000u; u.w ^= 0x80008000u;
    return u;
}

__device__ inline f32x4 mfma16(bf16x8 a, bf16x8 b, f32x4 c) {
    return __builtin_amdgcn_mfma_f32_16x16x32_bf16(a, b, c, 0, 0, 0);
}

// guarded float4 load: element index d within row pointer p, limit dlim
__device__ inline f32x4 ld4g(const float* __restrict__ p, int d, int dlim) {
    f32x4 r;
    if (d + 4 <= dlim) {
        float4 v = *reinterpret_cast<const float4*>(p + d);
        r[0] = v.x; r[1] = v.y; r[2] = v.z; r[3] = v.w;
    } else {
        #pragma unroll
        for (int j = 0; j < 4; ++j) r[j] = (d + j < dlim) ? p[d + j] : 0.0f;
    }
    return r;
}

// guarded 8x bf16 (16B) load
__device__ inline uint4 ld8bf(const __bf16* __restrict__ p, int d, int dlim) {
    if (d + 8 <= dlim) return *reinterpret_cast<const uint4*>(p + d);
    union { uint4 u; __bf16 h[8]; } x;
    #pragma unroll
    for (int j = 0; j < 8; ++j) x.h[j] = (d + j < dlim) ? p[d + j] : (__bf16)0.0f;
    return x.u;
}

// pack two floats -> dword of 2 bf16 (lo = a, hi = b)
__device__ inline uint32_t pk(float a, float b) {
    union { __bf16 h[2]; uint32_t u; } x;
    x.h[0] = (__bf16)a; x.h[1] = (__bf16)b;
    return x.u;
}

// ---------------------------------------------------------------------------
// Phase 0: X f32 -> bf16
// ---------------------------------------------------------------------------
__global__ __launch_bounds__(256) void xbf_kernel(
    const float* __restrict__ Xre, const float* __restrict__ Xim,
    __bf16* __restrict__ XreB, __bf16* __restrict__ XimB)
{
    const int i = (blockIdx.x * 256 + threadIdx.x) * 4;
    if (i < B_DIM * D_DIM) {
        float4 a = *reinterpret_cast<const float4*>(Xre + i);
        float4 b = *reinterpret_cast<const float4*>(Xim + i);
        *(uint2*)(XreB + i) = make_uint2(pk(a.x, a.y), pk(a.z, a.w));
        *(uint2*)(XimB + i) = make_uint2(pk(b.x, b.y), pk(b.z, b.w));
    }
}

// ---------------------------------------------------------------------------
// Phase 1 (r6 version, best known): coeffs[b,k] = (sum_d X*conj(bases))*w[k].
// k-tile 128; KS=64; bases staged at 256B/instruction; X staged from bf16.
// Single-buffer LDS 55KB -> 2 blocks/CU. Grid x=ktg (xcd=ktg%8).
// ---------------------------------------------------------------------------
#define P1_STRIDE 72  // 64 d + 8 pad

template <bool XBF>
__global__ __launch_bounds__(256, 2) void p1_coeffs(
    const float* __restrict__ XreF, const float* __restrict__ XimF,
    const __bf16* __restrict__ XreB, const __bf16* __restrict__ XimB,
    const float* __restrict__ Bre, const float* __restrict__ Bim,
    const float* __restrict__ Wre, const float* __restrict__ Wim,
    float* __restrict__ Cre, float* __restrict__ Cim)
{
    __shared__ __align__(16) __bf16 sX[2][64][P1_STRIDE];     // [re/im][b][d]
    __shared__ __align__(16) __bf16 sB[2][KTILE][P1_STRIDE];  // [re/im][k][d]

    const int ktg = blockIdx.x;       // 16 k-groups of 128  (xcd = ktg%8)
    const int dc  = blockIdx.y;       // 32 d-chunks of 1024
    const int tid  = threadIdx.x;
    const int lane = tid & 63;
    const int w    = tid >> 6;
    const int r    = lane & 15;
    const int g    = lane >> 4;

    const int kbase  = ktg * KTILE;
    const int dstart = dc * 1024;
    const int dend   = min(dstart + 1024, D_DIM);
    const int nsteps = (dend - dstart + 63) >> 6;

    const int srow = tid >> 4;          // 0..15 (+16 per j)
    const int sd   = (tid & 15) * 4;    // f32 elems 0..60
    const int rowx = tid >> 3;          // 0..31 (+32 per j)
    const int colx = (tid & 7) * 8;     // bf16 elems 0..56

    f32x4 bst[16];
    uint4 xst[4];
    f32x4 xstf[8];

    auto LOADS = [&](int s) {
        const int dg = dstart + s * 64 + sd;
        #pragma unroll
        for (int j = 0; j < 8; ++j) {
            const int row = j * 16 + srow;
            bst[j]     = ld4g(Bre + (size_t)(kbase + row) * D_DIM, dg, dend);
            bst[8 + j] = ld4g(Bim + (size_t)(kbase + row) * D_DIM, dg, dend);
        }
        if (XBF) {
            const int dgx = dstart + s * 64 + colx;
            xst[0] = ld8bf(XreB + (size_t)rowx * D_DIM,        dgx, dend);
            xst[1] = ld8bf(XreB + (size_t)(rowx + 32) * D_DIM, dgx, dend);
            xst[2] = ld8bf(XimB + (size_t)rowx * D_DIM,        dgx, dend);
            xst[3] = ld8bf(XimB + (size_t)(rowx + 32) * D_DIM, dgx, dend);
        } else {
            #pragma unroll
            for (int j = 0; j < 4; ++j) {
                const int row = j * 16 + srow;
                xstf[j]     = ld4g(XreF + (size_t)row * D_DIM, dg, dend);
                xstf[4 + j] = ld4g(XimF + (size_t)row * D_DIM, dg, dend);
            }
        }
    };

    auto WRITE = [&]() {
        #pragma unroll
        for (int j = 0; j < 8; ++j) {
            const int row = j * 16 + srow;
            *(uint2*)&sB[0][row][sd] = make_uint2(pk(bst[j][0],     bst[j][1]),     pk(bst[j][2],     bst[j][3]));
            *(uint2*)&sB[1][row][sd] = make_uint2(pk(bst[8 + j][0], bst[8 + j][1]), pk(bst[8 + j][2], bst[8 + j][3]));
        }
        if (XBF) {
            *(uint4*)&sX[0][rowx][colx]      = xst[0];
            *(uint4*)&sX[0][rowx + 32][colx] = xst[1];
            *(uint4*)&sX[1][rowx][colx]      = xst[2];
            *(uint4*)&sX[1][rowx + 32][colx] = xst[3];
        } else {
            #pragma unroll
            for (int j = 0; j < 4; ++j) {
                const int row = j * 16 + srow;
                *(uint2*)&sX[0][row][sd] = make_uint2(pk(xstf[j][0],     xstf[j][1]),     pk(xstf[j][2],     xstf[j][3]));
                *(uint2*)&sX[1][row][sd] = make_uint2(pk(xstf[4 + j][0], xstf[4 + j][1]), pk(xstf[4 + j][2], xstf[4 + j][3]));
            }
        }
    };

    const int m0  = (w & 1) * 32;     // local b quadrant (32 rows)
    const int nl0 = (w >> 1) * 64;    // local k span (64 cols)

    f32x4 accRe[2][4] = {};
    f32x4 accIm[2][4] = {};

    auto COMPUTE = [&]() {
        #pragma unroll
        for (int kk = 0; kk < 2; ++kk) {
            const int dp = kk * 32 + g * 8;
            uint4 xre[2], xim[2], bre[4], bim[4];
            #pragma unroll
            for (int ms = 0; ms < 2; ++ms) {
                xre[ms] = *(const uint4*)&sX[0][m0 + ms * 16 + r][dp];
                xim[ms] = *(const uint4*)&sX[1][m0 + ms * 16 + r][dp];
            }
            #pragma unroll
            for (int ns = 0; ns < 4; ++ns) {
                bre[ns] = *(const uint4*)&sB[0][nl0 + ns * 16 + r][dp];
                bim[ns] = *(const uint4*)&sB[1][nl0 + ns * 16 + r][dp];
            }
            #pragma unroll
            for (int ms = 0; ms < 2; ++ms)
            #pragma unroll
            for (int ns = 0; ns < 4; ++ns) {
                // C_re += Xre*Bre + Xim*Bim ; C_im += Xim*Bre - Xre*Bim
                accRe[ms][ns] = mfma16(asbf(xre[ms]), asbf(bre[ns]), accRe[ms][ns]);
                accRe[ms][ns] = mfma16(asbf(xim[ms]), asbf(bim[ns]), accRe[ms][ns]);
                accIm[ms][ns] = mfma16(asbf(xim[ms]), asbf(bre[ns]), accIm[ms][ns]);
                accIm[ms][ns] = mfma16(asbf(neg4(xre[ms])), asbf(bim[ns]), accIm[ms][ns]);
            }
        }
    };

    LOADS(0); WRITE(); __syncthreads();
    for (int s = 0; s < nsteps; ++s) {
        if (s + 1 < nsteps) LOADS(s + 1);
        COMPUTE();
        if (s + 1 < nsteps) {
            __syncthreads();   // all reads of the buffer done
            WRITE();           // overwrite with s+1 tile
            __syncthreads();   // writes visible
        }
    }

    // epilogue: scale by w[k], atomic accumulate (C/D: col=lane&15, row=g*4+i)
    #pragma unroll
    for (int ms = 0; ms < 2; ++ms)
    #pragma unroll
    for (int ns = 0; ns < 4; ++ns) {
        const int kb = kbase + nl0 + ns * 16 + r;
        const float wre = Wre[kb], wim = Wim[kb];
        #pragma unroll
        for (int i = 0; i < 4; ++i) {
            const int b = m0 + ms * 16 + g * 4 + i;
            const float cre = accRe[ms][ns][i];
            const float cim = accIm[ms][ns][i];
            atomicAdd(&Cre[b * K_DIM + kb], cre * wre - cim * wim);
            atomicAdd(&Cim[b * K_DIM + kb], cre * wim + cim * wre);
        }
    }
}

// ---------------------------------------------------------------------------
// Phase 1.5: coeffs f32 -> bf16
// ---------------------------------------------------------------------------
__global__ __launch_bounds__(256) void cbf_kernel(
    const float* __restrict__ Cre, const float* __restrict__ Cim,
    __bf16* __restrict__ CreBf, __bf16* __restrict__ CimBf)
{
    const int i = blockIdx.x * 256 + threadIdx.x;
    if (i < B_DIM * K_DIM) {
        CreBf[i] = (__bf16)Cre[i];
        CimBf[i] = (__bf16)Cim[i];
    }
}

// ---------------------------------------------------------------------------
// Phase 2 v2: out[b,d] += sum_{k in half} coeffs[b,k] * bases[k,d].
// WD=128: bases rows visited in 512B per instruction (32 lanes x float4,
// 2 rows/instr). Thread holds 8 consecutive k-rows -> register-packed
// transpose into [d][k] LDS via uint2 writes. True double-buffer (72 KB,
// 2 blocks/CU), ONE barrier per step. Grid 254 x 2 k-halves.
// ---------------------------------------------------------------------------
#define P2_WD 128
#define P2_STRIDE 72  // 64 k + 8 pad per d-row

template <bool WIM>
__global__ __launch_bounds__(256, 2) void p2_project(
    const float* __restrict__ Bre, const float* __restrict__ Bim,
    const __bf16* __restrict__ CreBf, const __bf16* __restrict__ CimBf,
    float* __restrict__ out)
{
    __shared__ __align__(16) __bf16 sT[2][2][P2_WD][P2_STRIDE];  // [buf][mat][d][k]

    const int dt = blockIdx.x;
    const int kh = blockIdx.y;        // k half: 0 -> [0,1024), 1 -> [1024,2048)
    const int d0 = dt * P2_WD;
    const int khbase = kh * (K_DIM / 2);
    const int tid  = threadIdx.x;
    const int lane = tid & 63;
    const int w    = tid >> 6;
    const int r    = lane & 15;
    const int g    = lane >> 4;

    // staging: rowgrp = tid>>5 (0..7) -> k-rows rowgrp*8 .. rowgrp*8+7;
    // sd = (tid&31)*4 -> 512B contiguous per 2-row pair per instruction.
    const int rowgrp = tid >> 5;
    const int sd     = (tid & 31) * 4;

    f32x4 st[16];  // 8 consecutive k-rows x {re, im}

    auto LOADS = [&](int t) {
        const int k0 = khbase + t * 64 + rowgrp * 8;
        #pragma unroll
        for (int j = 0; j < 8; ++j) {
            const size_t ro = (size_t)(k0 + j) * D_DIM;
            st[j]     = ld4g(Bre + ro, d0 + sd, D_DIM);
            st[8 + j] = ld4g(Bim + ro, d0 + sd, D_DIM);
        }
    };

    auto WRITE = [&](int buf) {
        const int kloc = rowgrp * 8;
        #pragma unroll
        for (int i = 0; i < 4; ++i) {
            *(uint2*)&sT[buf][0][sd + i][kloc] =
                make_uint2(pk(st[0][i], st[1][i]), pk(st[2][i], st[3][i]));
            *(uint2*)&sT[buf][0][sd + i][kloc + 4] =
                make_uint2(pk(st[4][i], st[5][i]), pk(st[6][i], st[7][i]));
            *(uint2*)&sT[buf][1][sd + i][kloc] =
                make_uint2(pk(st[8][i], st[9][i]), pk(st[10][i], st[11][i]));
            *(uint2*)&sT[buf][1][sd + i][kloc + 4] =
                make_uint2(pk(st[12][i], st[13][i]), pk(st[14][i], st[15][i]));
        }
    };

    const int m0  = (w & 1) * 32;     // b quadrant
    const int nl0 = (w >> 1) * 64;    // local d span (64 cols)

    f32x4 accRe[2][4] = {};
    f32x4 accIm[2][4] = {};

    auto COMPUTE = [&](int t, int buf) {
        const int k0 = khbase + t * 64;
        uint4 aRe[2][2], aIm[2][2];
        #pragma unroll
        for (int ms = 0; ms < 2; ++ms) {
            const size_t rowo = (size_t)(m0 + ms * 16 + r) * K_DIM;
            #pragma unroll
            for (int kk = 0; kk < 2; ++kk) {
                aRe[ms][kk] = *(const uint4*)&CreBf[rowo + k0 + kk * 32 + g * 8];
                aIm[ms][kk] = *(const uint4*)&CimBf[rowo + k0 + kk * 32 + g * 8];
            }
        }
        #pragma unroll
        for (int kk = 0; kk < 2; ++kk) {
            uint4 bre[4], bim[4];
            #pragma unroll
            for (int ns = 0; ns < 4; ++ns) {
                bre[ns] = *(const uint4*)&sT[buf][0][nl0 + ns * 16 + r][kk * 32 + g * 8];
                bim[ns] = *(const uint4*)&sT[buf][1][nl0 + ns * 16 + r][kk * 32 + g * 8];
            }
            #pragma unroll
            for (int ms = 0; ms < 2; ++ms)
            #pragma unroll
            for (int ns = 0; ns < 4; ++ns) {
                // out_re += cre*Bre - cim*Bim ; out_im += cre*Bim + cim*Bre
                accRe[ms][ns] = mfma16(asbf(aRe[ms][kk]), asbf(bre[ns]), accRe[ms][ns]);
                accRe[ms][ns] = mfma16(asbf(neg4(aIm[ms][kk])), asbf(bim[ns]), accRe[ms][ns]);
                if (WIM) {
                    accIm[ms][ns] = mfma16(asbf(aRe[ms][kk]), asbf(bim[ns]), accIm[ms][ns]);
                    accIm[ms][ns] = mfma16(asbf(aIm[ms][kk]), asbf(bre[ns]), accIm[ms][ns]);
                }
            }
        }
    };

    const int NT = (K_DIM / 2) / 64;  // 16
    LOADS(0); WRITE(0); __syncthreads();
    for (int t = 0; t < NT; ++t) {
        if (t + 1 < NT) LOADS(t + 1);
        COMPUTE(t, t & 1);
        if (t + 1 < NT) WRITE((t + 1) & 1);  // other buffer: no race with COMPUTE
        __syncthreads();
    }

    #pragma unroll
    for (int ms = 0; ms < 2; ++ms)
    #pragma unroll
    for (int ns = 0; ns < 4; ++ns) {
        const int d = d0 + nl0 + ns * 16 + r;
        if (d < D_DIM) {
            #pragma unroll
            for (int i = 0; i < 4; ++i) {
                const int b = m0 + ms * 16 + g * 4 + i;
                if (!WIM) {
                    atomicAdd(&out[(size_t)b * D_DIM + d], accRe[ms][ns][i]);
                } else {
                    atomicAdd(&out[((size_t)b * D_DIM + d) * 2],     accRe[ms][ns][i]);
                    atomicAdd(&out[((size_t)b * D_DIM + d) * 2 + 1], accIm[ms][ns][i]);
                }
            }
        }
    }
}

extern "C" void kernel_launch(void* const* d_in, const int* in_sizes, int n_in,
                              void* d_out, int out_size, void* d_ws, size_t ws_size,
                              hipStream_t stream) {
    const float* Xre = (const float*)d_in[0];
    const float* Xim = (const float*)d_in[1];
    const float* Bre = (const float*)d_in[2];
    const float* Bim = (const float*)d_in[3];
    const float* Wre = (const float*)d_in[4];
    const float* Wim = (const float*)d_in[5];

    float*  Cre   = (float*)d_ws;                          // 512 KB
    float*  Cim   = Cre + B_DIM * K_DIM;                   // 512 KB
    __bf16* CreBf = (__bf16*)(Cim + B_DIM * K_DIM);        // 256 KB
    __bf16* CimBf = CreBf + B_DIM * K_DIM;                 // 256 KB
    __bf16* XreB  = CimBf + B_DIM * K_DIM;                 // 4.15 MB
    __bf16* XimB  = XreB + (size_t)B_DIM * D_DIM;          // 4.15 MB

    const size_t need = (size_t)2 * B_DIM * K_DIM * sizeof(float)
                      + (size_t)2 * B_DIM * K_DIM * sizeof(__bf16)
                      + (size_t)2 * B_DIM * D_DIM * sizeof(__bf16);
    const bool xbf = ws_size >= need;

    (void)hipMemsetAsync(d_ws, 0, (size_t)2 * B_DIM * K_DIM * sizeof(float), stream);
    (void)hipMemsetAsync(d_out, 0, (size_t)out_size * sizeof(float), stream);

    dim3 g1(K_DIM / KTILE, 32);  // x = k-group (drives XCD assignment), y = d-chunk
    if (xbf) {
        xbf_kernel<<<(B_DIM * D_DIM / 4 + 255) / 256, 256, 0, stream>>>(Xre, Xim, XreB, XimB);
        p1_coeffs<true><<<g1, 256, 0, stream>>>(Xre, Xim, XreB, XimB, Bre, Bim, Wre, Wim, Cre, Cim);
    } else {
        p1_coeffs<false><<<g1, 256, 0, stream>>>(Xre, Xim, XreB, XimB, Bre, Bim, Wre, Wim, Cre, Cim);
    }

    cbf_kernel<<<(B_DIM * K_DIM + 255) / 256, 256, 0, stream>>>(Cre, Cim, CreBf, CimBf);

    const int ndt = (D_DIM + P2_WD - 1) / P2_WD;  // 254
    dim3 g2(ndt, 2);
    if (out_size == 2 * B_DIM * D_DIM) {
        p2_project<true><<<g2, 256, 0, stream>>>(Bre, Bim, CreBf, CimBf, (float*)d_out);
    } else {
        p2_project<false><<<g2, 256, 0, stream>>>(Bre, Bim, CreBf, CimBf, (float*)d_out);
    }
}